// Round 1
// baseline (2129.105 us; speedup 1.0000x reference)
//
#include <hip/hip_runtime.h>
#include <hip/hip_bf16.h>

// Problem constants
#define HWPX 16384      // 128*128
#define W128 128

// ---------------- K1a: LayerNorm stats per (bb, pixel) ----------------
__global__ __launch_bounds__(256) void k_stats(const float* __restrict__ x,
                                               float2* __restrict__ stats) {
  int idx = blockIdx.x * 256 + threadIdx.x;   // 32*16384 total
  int bb = idx >> 14;
  int p = idx & (HWPX - 1);
  const float* xp = x + ((size_t)bb << 20) + p;   // bb*64*16384 + p
  float s = 0.f, s2 = 0.f;
#pragma unroll
  for (int ci = 0; ci < 64; ++ci) {
    float v = xp[(size_t)ci << 14];
    s += v;
    s2 = fmaf(v, v, s2);
  }
  float mu = s * (1.f / 64.f);
  float var = fmaf(-mu, mu, s2 * (1.f / 64.f));
  stats[idx] = make_float2(mu, rsqrtf(var + 1e-5f));
}

// ---------------- K1b: LN + temporal 1x1 (16->48) + dw3x3 + attn partials ----
// grid: (64 tiles of 16x16, 128 = bt*64+ci), block 256
__global__ __launch_bounds__(256) void k_qkvdw(
    const float* __restrict__ x, const float2* __restrict__ stats,
    const float* __restrict__ lnw, const float* __restrict__ lnb,
    const float* __restrict__ qkvw, const float* __restrict__ dww,
    float* __restrict__ vbuf, float* __restrict__ Sacc, float* __restrict__ Nacc) {
  __shared__ float smem[2 * 16 * 324];   // [xn 16x324 | pre 16x324]; later qk[32][258]
  float* xn = smem;
  float* pre = smem + 16 * 324;

  int bc = blockIdx.y;            // bt*64 + ci
  int bt = bc >> 6;
  int ci = bc & 63;
  int ty = (blockIdx.x >> 3) << 4;
  int tx = (blockIdx.x & 7) << 4;
  float lw = lnw[ci], lb = lnb[ci];

  // Phase 1: LN'd halo tile (18x18) for all 16 temporal frames into LDS.
  for (int hp = threadIdx.x; hp < 324; hp += 256) {
    int hy = hp / 18;
    int hx = hp - hy * 18;
    int gy = ty + hy - 1, gx = tx + hx - 1;
    bool ok = ((unsigned)gy < 128u) && ((unsigned)gx < 128u);
    int p = (gy << 7) + gx;
#pragma unroll
    for (int t = 0; t < 16; ++t) {
      float v = 0.f;
      if (ok) {
        int bb = (bt << 4) + t;
        float xv = x[((((size_t)bb << 6) + ci) << 14) + p];
        float2 st = stats[(bb << 14) + p];
        v = fmaf((xv - st.x) * st.y, lw, lb);
      }
      xn[t * 324 + hp] = v;   // zero at padding => pre-dw qkv zero-padded (1x1, no bias)
    }
  }
  __syncthreads();

  int ip = threadIdx.x;
  int iy = ip >> 4, ix = ip & 15;
  float qreg[16], kreg[16];

#pragma unroll
  for (int chunk = 0; chunk < 3; ++chunk) {   // q, k, v channel chunks of 16
    // Phase a: temporal 1x1 for this chunk into pre LDS (halo included)
    for (int hp = threadIdx.x; hp < 324; hp += 256) {
      float xr[16];
#pragma unroll
      for (int t = 0; t < 16; ++t) xr[t] = xn[t * 324 + hp];
#pragma unroll
      for (int o = 0; o < 16; ++o) {
        float s = 0.f;
#pragma unroll
        for (int t = 0; t < 16; ++t)
          s = fmaf(qkvw[((chunk * 16 + o) << 4) + t], xr[t], s);   // uniform -> s_load
        pre[o * 324 + hp] = s;
      }
    }
    __syncthreads();

    // Phase b: depthwise 3x3 for interior pixel
    float acc[16];
#pragma unroll
    for (int o = 0; o < 16; ++o) {
      float s = 0.f;
#pragma unroll
      for (int dy = 0; dy < 3; ++dy)
#pragma unroll
        for (int dx = 0; dx < 3; ++dx)
          s = fmaf(dww[(chunk * 16 + o) * 9 + dy * 3 + dx],
                   pre[o * 324 + (iy + dy) * 18 + (ix + dx)], s);
      acc[o] = s;
    }
    if (chunk == 0) {
#pragma unroll
      for (int o = 0; o < 16; ++o) qreg[o] = acc[o];
    } else if (chunk == 1) {
#pragma unroll
      for (int o = 0; o < 16; ++o) kreg[o] = acc[o];
    } else {
      int p = ((ty + iy) << 7) + tx + ix;
      float* vp = vbuf + (((size_t)bc << 4) << 14) + p;
#pragma unroll
      for (int o = 0; o < 16; ++o) vp[(size_t)o << 14] = acc[o];
    }
    __syncthreads();   // protect pre/xn before reuse
  }

  // Phase c: block-level attention partial sums through LDS (stride 258 vs banks)
  float* qk = smem;   // [32][258], aliases xn+pre (10368 floats >= 32*258=8256)
#pragma unroll
  for (int o = 0; o < 16; ++o) {
    qk[o * 258 + ip] = qreg[o];
    qk[(o + 16) * 258 + ip] = kreg[o];
  }
  __syncthreads();
  {
    // S[hd][c][d]: 64 combos x 4 pixel-chunks (interleaved px = pc + 4i)
    int combo = threadIdx.x >> 2;
    int hd = combo >> 4, c = (combo >> 2) & 3, d = combo & 3;
    int pc = threadIdx.x & 3;
    const float* qrow = qk + (hd * 4 + c) * 258;
    const float* krow = qk + (16 + hd * 4 + d) * 258;
    float s = 0.f;
#pragma unroll
    for (int i = 0; i < 64; ++i) {
      int px = pc + (i << 2);
      s = fmaf(qrow[px], krow[px], s);
    }
    atomicAdd(&Sacc[((bc << 2) + hd) * 16 + c * 4 + d], s);
  }
  {
    // norms: 32 rows (16 q + 16 k) x 8 pixel-chunks (interleaved px = pc + 8i)
    int combo = threadIdx.x >> 3;
    int pc = threadIdx.x & 7;
    const float* row = qk + combo * 258;
    float s = 0.f;
#pragma unroll
    for (int i = 0; i < 32; ++i) {
      float v = row[pc + (i << 3)];
      s = fmaf(v, v, s);
    }
    atomicAdd(&Nacc[(bc << 5) + combo], s);
  }
}

// ---------------- K2: 4x4 softmax per (b, head) ----------------
__global__ __launch_bounds__(256) void k_softmax(
    const float* __restrict__ Sacc, const float* __restrict__ Nacc,
    const float* __restrict__ temp, float* __restrict__ attn) {
  int idx = blockIdx.x * 256 + threadIdx.x;
  if (idx >= 512) return;
  int b = idx >> 2, hd = idx & 3;
  float tp = temp[hd];
  float iq[4], ik[4];
#pragma unroll
  for (int c = 0; c < 4; ++c) {
    iq[c] = 1.f / fmaxf(sqrtf(Nacc[(b << 5) + (hd << 2) + c]), 1e-12f);
    ik[c] = 1.f / fmaxf(sqrtf(Nacc[(b << 5) + 16 + (hd << 2) + c]), 1e-12f);
  }
  const float* Sp = Sacc + ((b << 2) + hd) * 16;
  float* ap = attn + ((b << 2) + hd) * 16;
#pragma unroll
  for (int c = 0; c < 4; ++c) {
    float l[4];
#pragma unroll
    for (int d = 0; d < 4; ++d) l[d] = Sp[c * 4 + d] * iq[c] * ik[d] * tp;
    float m = fmaxf(fmaxf(l[0], l[1]), fmaxf(l[2], l[3]));
    float e0 = expf(l[0] - m), e1 = expf(l[1] - m);
    float e2 = expf(l[2] - m), e3 = expf(l[3] - m);
    float inv = 1.f / (e0 + e1 + e2 + e3);
    ap[c * 4 + 0] = e0 * inv;
    ap[c * 4 + 1] = e1 * inv;
    ap[c * 4 + 2] = e2 * inv;
    ap[c * 4 + 3] = e3 * inv;
  }
}

// ---------------- K3: out = proj @ (attn . v), fused ----------------
// grid: (256 pixel strips of 64, 8 = bt*4+hd), block 256 (wave = temporal row c)
__global__ __launch_bounds__(256) void k_outproj(
    const float* __restrict__ vbuf, const float* __restrict__ attn,
    const float* __restrict__ projw, float* __restrict__ out) {
  int bt = blockIdx.y >> 2, hd = blockIdx.y & 3;
  int px = blockIdx.x * 64 + (threadIdx.x & 63);
  int c = threadIdx.x >> 6;   // wave id = temporal row within head

  __shared__ float attn_lds[64 * 16];
  for (int e = threadIdx.x; e < 1024; e += 256) {
    int ci = e >> 4, r = e & 15;
    attn_lds[e] = attn[(((bt * 64 + ci) << 2) + hd) * 16 + r];
  }
  __syncthreads();

  float acc[64];
#pragma unroll
  for (int o = 0; o < 64; ++o) acc[o] = 0.f;

  const float* vb = vbuf + ((size_t)((bt << 10) + (hd << 2)) << 14) + px;
  for (int ci = 0; ci < 64; ++ci) {
    const float* vp = vb + ((size_t)ci << 18);
    float v0 = vp[0];
    float v1 = vp[(size_t)1 << 14];
    float v2 = vp[(size_t)2 << 14];
    float v3 = vp[(size_t)3 << 14];
    const float* al = attn_lds + (ci << 4) + (c << 2);   // wave-uniform -> broadcast
    float y = al[0] * v0;
    y = fmaf(al[1], v1, y);
    y = fmaf(al[2], v2, y);
    y = fmaf(al[3], v3, y);
#pragma unroll
    for (int o = 0; o < 64; ++o)
      acc[o] = fmaf(projw[(o << 6) + ci], y, acc[o]);   // uniform -> SGPR operand
  }
  float* op = out + ((size_t)(((bt << 4) + (hd << 2) + c) << 6) << 14) + px;
#pragma unroll
  for (int o = 0; o < 64; ++o) op[(size_t)o << 14] = acc[o];
}

extern "C" void kernel_launch(void* const* d_in, const int* in_sizes, int n_in,
                              void* d_out, int out_size, void* d_ws, size_t ws_size,
                              hipStream_t stream) {
  const float* x = (const float*)d_in[0];
  const float* lnw = (const float*)d_in[1];
  const float* lnb = (const float*)d_in[2];
  const float* qkvw = (const float*)d_in[3];
  const float* dww = (const float*)d_in[4];
  const float* projw = (const float*)d_in[5];
  const float* temp = (const float*)d_in[6];
  float* out = (float*)d_out;

  float* ws = (float*)d_ws;
  float* vbuf = ws;                                  // 33,554,432 floats (128 MiB)
  float2* stats = (float2*)(ws + 33554432);          // 32*16384 float2 (4 MiB)
  float* Sacc = ws + 33554432 + 1048576;             // 128*4*16 = 8192
  float* Nacc = Sacc + 8192;                         // 128*32  = 4096
  float* attn = Nacc + 4096;                         // 128*4*16 = 8192

  // zero the atomic accumulators every call (graph-capturable)
  hipMemsetAsync(Sacc, 0, (8192 + 4096) * sizeof(float), stream);

  k_stats<<<dim3(2048), dim3(256), 0, stream>>>(x, stats);
  k_qkvdw<<<dim3(64, 128), dim3(256), 0, stream>>>(x, stats, lnw, lnb, qkvw, dww,
                                                   vbuf, Sacc, Nacc);
  k_softmax<<<dim3(2), dim3(256), 0, stream>>>(Sacc, Nacc, temp, attn);
  k_outproj<<<dim3(256, 8), dim3(256), 0, stream>>>(vbuf, attn, projw, out);
}

// Round 2
// 421.019 us; speedup vs baseline: 5.0570x; 5.0570x over previous
//
#include <hip/hip_runtime.h>
#include <hip/hip_fp16.h>

__device__ __forceinline__ float2 h2f2(unsigned int u) {
  return __half22float2(__builtin_bit_cast(__half2, u));
}
__device__ __forceinline__ unsigned int f2h2(float a, float b) {
  return __builtin_bit_cast(unsigned int, __floats2half2_rn(a, b));
}

// ---------------- K0: LayerNorm stats per (bb, pixel-pair) ----------------
__global__ __launch_bounds__(256) void k_stats(const float2* __restrict__ x2,
                                               float4* __restrict__ stats4) {
  int id = blockIdx.x * 256 + threadIdx.x;   // 32 * 8192
  int bb = id >> 13;
  int jp = id & 8191;
  const float2* xp = x2 + ((size_t)bb << 19) + jp;
  float s0 = 0.f, q0 = 0.f, s1 = 0.f, q1 = 0.f;
#pragma unroll
  for (int ci = 0; ci < 64; ++ci) {
    float2 v = xp[(size_t)ci << 13];
    s0 += v.x; q0 = fmaf(v.x, v.x, q0);
    s1 += v.y; q1 = fmaf(v.y, v.y, q1);
  }
  float mu0 = s0 * (1.f / 64.f), mu1 = s1 * (1.f / 64.f);
  float4 r;
  r.x = mu0; r.y = rsqrtf(fmaf(-mu0, mu0, q0 * (1.f / 64.f)) + 1e-5f);
  r.z = mu1; r.w = rsqrtf(fmaf(-mu1, mu1, q1 * (1.f / 64.f)) + 1e-5f);
  stats4[id] = r;
}

// ---------------- K1: LN + temporal 1x1 -> fp16 channel-pair planes -------
// grid (32, 128), thread = 2 pixels. NO2 = number of channel pairs produced.
template <int NO2>
__global__ __launch_bounds__(256) void k_pre(
    const float2* __restrict__ x2, const float4* __restrict__ stats4,
    const float* __restrict__ lnw, const float* __restrict__ lnb,
    const float* __restrict__ qkvw, unsigned int* __restrict__ preOut, int chbase) {
  int bc = blockIdx.y, bt = bc >> 6, ci = bc & 63;
  int jp = blockIdx.x * 256 + threadIdx.x;   // pixel-pair index [0,8192)
  float lw = lnw[ci], lb = lnb[ci];
  float a0[2 * NO2], a1[2 * NO2];
#pragma unroll
  for (int o = 0; o < 2 * NO2; ++o) { a0[o] = 0.f; a1[o] = 0.f; }
#pragma unroll
  for (int t = 0; t < 16; ++t) {
    int bb = (bt << 4) + t;
    float2 xv = x2[(((size_t)bb << 6) + ci) * 8192 + jp];
    float4 st = stats4[((size_t)bb << 13) + jp];
    float xn0 = fmaf((xv.x - st.x) * st.y, lw, lb);
    float xn1 = fmaf((xv.y - st.z) * st.w, lw, lb);
#pragma unroll
    for (int o = 0; o < 2 * NO2; ++o) {
      float w = qkvw[((chbase + o) << 4) + t];
      a0[o] = fmaf(w, xn0, a0[o]);
      a1[o] = fmaf(w, xn1, a1[o]);
    }
  }
#pragma unroll
  for (int o2 = 0; o2 < NO2; ++o2) {
    uint2 st2;
    st2.x = f2h2(a0[2 * o2], a0[2 * o2 + 1]);   // (chEven, chOdd) @ px0
    st2.y = f2h2(a1[2 * o2], a1[2 * o2 + 1]);   // @ px1
    size_t plane = (size_t)bc * NO2 + o2;
    *reinterpret_cast<uint2*>(preOut + (plane << 14) + 2 * jp) = st2;
  }
}

// ---------------- K2: dw3x3 on q,k + attention partial sums ---------------
// grid (32, 128): tile 32x16 px per block; 16 half2 planes (32 channels)
__global__ __launch_bounds__(256) void k_dwqk(
    const unsigned int* __restrict__ pre, const float* __restrict__ dww,
    float* __restrict__ Sacc, float* __restrict__ Nacc) {
  __shared__ unsigned int lds[10080];   // stage [16][18*35] / later qk [32][258]
  int tid = threadIdx.x;
  int bc = blockIdx.y;
  int tx0 = (blockIdx.x & 3) << 5;
  int ty0 = (blockIdx.x >> 2) << 4;
  size_t planeBase = (size_t)bc << 4;
  for (int f = tid; f < 9792; f += 256) {
    int o2 = f / 612;
    int r = f - o2 * 612;
    int hy = r / 34;
    int hx = r - hy * 34;
    int gy = ty0 + hy - 1, gx = tx0 + hx - 1;
    unsigned int val = 0;
    if ((unsigned)gy < 128u && (unsigned)gx < 128u)
      val = pre[((planeBase + o2) << 14) + (gy << 7) + gx];
    lds[o2 * 630 + hy * 35 + hx] = val;
  }
  __syncthreads();
  int iy = tid >> 4, jx = tid & 15;
  float accA[32], accB[32];   // per-channel value at px0 / px1
#pragma unroll
  for (int o2 = 0; o2 < 16; ++o2) {
    float s00 = 0.f, s01 = 0.f, s10 = 0.f, s11 = 0.f;
    const float* wE = dww + (2 * o2) * 9;
    const float* wO = dww + (2 * o2 + 1) * 9;
    int base = o2 * 630 + iy * 35 + 2 * jx;
#pragma unroll
    for (int dy = 0; dy < 3; ++dy) {
      float2 d0 = h2f2(lds[base + dy * 35 + 0]);
      float2 d1 = h2f2(lds[base + dy * 35 + 1]);
      float2 d2 = h2f2(lds[base + dy * 35 + 2]);
      float2 d3 = h2f2(lds[base + dy * 35 + 3]);
      float w0 = wE[dy * 3], w1 = wE[dy * 3 + 1], w2 = wE[dy * 3 + 2];
      s00 = fmaf(w0, d0.x, s00); s00 = fmaf(w1, d1.x, s00); s00 = fmaf(w2, d2.x, s00);
      s01 = fmaf(w0, d1.x, s01); s01 = fmaf(w1, d2.x, s01); s01 = fmaf(w2, d3.x, s01);
      float u0 = wO[dy * 3], u1 = wO[dy * 3 + 1], u2 = wO[dy * 3 + 2];
      s10 = fmaf(u0, d0.y, s10); s10 = fmaf(u1, d1.y, s10); s10 = fmaf(u2, d2.y, s10);
      s11 = fmaf(u0, d1.y, s11); s11 = fmaf(u1, d2.y, s11); s11 = fmaf(u2, d3.y, s11);
    }
    accA[2 * o2] = s00; accB[2 * o2] = s01;
    accA[2 * o2 + 1] = s10; accB[2 * o2 + 1] = s11;
  }
  __syncthreads();
#pragma unroll
  for (int ch = 0; ch < 32; ++ch)
    lds[ch * 258 + tid] = f2h2(accA[ch], accB[ch]);
  __syncthreads();
  {
    int combo = tid >> 2, pc = tid & 3;
    int hd = combo >> 4, cc = (combo >> 2) & 3, dd = combo & 3;
    const unsigned int* qrow = lds + (hd * 4 + cc) * 258;
    const unsigned int* krow = lds + (16 + hd * 4 + dd) * 258;
    float s = 0.f;
#pragma unroll
    for (int i = 0; i < 64; ++i) {
      int col = pc + (i << 2);
      float2 q = h2f2(qrow[col]);
      float2 k = h2f2(krow[col]);
      s = fmaf(q.x, k.x, s);
      s = fmaf(q.y, k.y, s);
    }
    s += __shfl_xor(s, 1);
    s += __shfl_xor(s, 2);
    if (pc == 0) atomicAdd(&Sacc[((bc << 2) + hd) * 16 + cc * 4 + dd], s);
  }
  {
    int combo = tid >> 3, pc = tid & 7;
    const unsigned int* row = lds + combo * 258;
    float n = 0.f;
#pragma unroll
    for (int i = 0; i < 32; ++i) {
      float2 v = h2f2(row[pc + (i << 3)]);
      n = fmaf(v.x, v.x, n);
      n = fmaf(v.y, v.y, n);
    }
    n += __shfl_xor(n, 1);
    n += __shfl_xor(n, 2);
    n += __shfl_xor(n, 4);
    if (pc == 0) atomicAdd(&Nacc[(bc << 5) + combo], n);
  }
}

// ---------------- K3: dw3x3 on v -> vbuf (fp16 planes) --------------------
__global__ __launch_bounds__(256) void k_dwv(
    const unsigned int* __restrict__ pre, const float* __restrict__ dww,
    unsigned int* __restrict__ vbuf) {
  __shared__ unsigned int lds[5040];   // [8][18*35]
  int tid = threadIdx.x;
  int bc = blockIdx.y;
  int tx0 = (blockIdx.x & 3) << 5;
  int ty0 = (blockIdx.x >> 2) << 4;
  size_t planeBase = (size_t)bc << 3;
  for (int f = tid; f < 4896; f += 256) {
    int o2 = f / 612;
    int r = f - o2 * 612;
    int hy = r / 34;
    int hx = r - hy * 34;
    int gy = ty0 + hy - 1, gx = tx0 + hx - 1;
    unsigned int val = 0;
    if ((unsigned)gy < 128u && (unsigned)gx < 128u)
      val = pre[((planeBase + o2) << 14) + (gy << 7) + gx];
    lds[o2 * 630 + hy * 35 + hx] = val;
  }
  __syncthreads();
  int iy = tid >> 4, jx = tid & 15;
#pragma unroll
  for (int o2 = 0; o2 < 8; ++o2) {
    float s00 = 0.f, s01 = 0.f, s10 = 0.f, s11 = 0.f;
    const float* wE = dww + (32 + 2 * o2) * 9;
    const float* wO = dww + (33 + 2 * o2) * 9;
    int base = o2 * 630 + iy * 35 + 2 * jx;
#pragma unroll
    for (int dy = 0; dy < 3; ++dy) {
      float2 d0 = h2f2(lds[base + dy * 35 + 0]);
      float2 d1 = h2f2(lds[base + dy * 35 + 1]);
      float2 d2 = h2f2(lds[base + dy * 35 + 2]);
      float2 d3 = h2f2(lds[base + dy * 35 + 3]);
      float w0 = wE[dy * 3], w1 = wE[dy * 3 + 1], w2 = wE[dy * 3 + 2];
      s00 = fmaf(w0, d0.x, s00); s00 = fmaf(w1, d1.x, s00); s00 = fmaf(w2, d2.x, s00);
      s01 = fmaf(w0, d1.x, s01); s01 = fmaf(w1, d2.x, s01); s01 = fmaf(w2, d3.x, s01);
      float u0 = wO[dy * 3], u1 = wO[dy * 3 + 1], u2 = wO[dy * 3 + 2];
      s10 = fmaf(u0, d0.y, s10); s10 = fmaf(u1, d1.y, s10); s10 = fmaf(u2, d2.y, s10);
      s11 = fmaf(u0, d1.y, s11); s11 = fmaf(u1, d2.y, s11); s11 = fmaf(u2, d3.y, s11);
    }
    uint2 st2;
    st2.x = f2h2(s00, s10);
    st2.y = f2h2(s01, s11);
    size_t idx = ((planeBase + o2) << 14) + (size_t)((ty0 + iy) << 7) + tx0 + 2 * jx;
    *reinterpret_cast<uint2*>(vbuf + idx) = st2;
  }
}

// ---------------- K4: 4x4 softmax per (b, head) ----------------
__global__ __launch_bounds__(256) void k_softmax(
    const float* __restrict__ Sacc, const float* __restrict__ Nacc,
    const float* __restrict__ temp, float* __restrict__ attn) {
  int idx = blockIdx.x * 256 + threadIdx.x;
  if (idx >= 512) return;
  int b = idx >> 2, hd = idx & 3;
  float tp = temp[hd];
  float iq[4], ik[4];
#pragma unroll
  for (int c = 0; c < 4; ++c) {
    iq[c] = 1.f / fmaxf(sqrtf(Nacc[(b << 5) + (hd << 2) + c]), 1e-12f);
    ik[c] = 1.f / fmaxf(sqrtf(Nacc[(b << 5) + 16 + (hd << 2) + c]), 1e-12f);
  }
  const float* Sp = Sacc + ((b << 2) + hd) * 16;
  float* ap = attn + ((b << 2) + hd) * 16;
#pragma unroll
  for (int c = 0; c < 4; ++c) {
    float l[4];
#pragma unroll
    for (int d = 0; d < 4; ++d) l[d] = Sp[c * 4 + d] * iq[c] * ik[d] * tp;
    float m = fmaxf(fmaxf(l[0], l[1]), fmaxf(l[2], l[3]));
    float e0 = expf(l[0] - m), e1 = expf(l[1] - m);
    float e2 = expf(l[2] - m), e3 = expf(l[3] - m);
    float inv = 1.f / (e0 + e1 + e2 + e3);
    ap[c * 4 + 0] = e0 * inv;
    ap[c * 4 + 1] = e1 * inv;
    ap[c * 4 + 2] = e2 * inv;
    ap[c * 4 + 3] = e3 * inv;
  }
}

// ---------------- K5: out = proj @ (attn . v), fused ----------------
__global__ __launch_bounds__(256) void k_outproj(
    const unsigned int* __restrict__ vbuf, const float* __restrict__ attn,
    const float* __restrict__ projw, float* __restrict__ out) {
  int bt = blockIdx.y >> 2, hd = blockIdx.y & 3;
  int px = blockIdx.x * 64 + (threadIdx.x & 63);
  int c = threadIdx.x >> 6;   // wave id = temporal row within head

  __shared__ float attn_lds[64 * 16];
  for (int e = threadIdx.x; e < 1024; e += 256) {
    int ci = e >> 4, r = e & 15;
    attn_lds[e] = attn[(((bt * 64 + ci) << 2) + hd) * 16 + r];
  }
  __syncthreads();

  float acc[64];
#pragma unroll
  for (int o = 0; o < 64; ++o) acc[o] = 0.f;

  size_t base = ((((size_t)bt * 64) * 8 + hd * 2) << 14) + px;
  for (int ci = 0; ci < 64; ++ci) {
    size_t off = base + (((size_t)ci * 8) << 14);
    float2 v01 = h2f2(vbuf[off]);
    float2 v23 = h2f2(vbuf[off + (1 << 14)]);
    const float* al = attn_lds + (ci << 4) + (c << 2);   // wave-uniform
    float y = al[0] * v01.x;
    y = fmaf(al[1], v01.y, y);
    y = fmaf(al[2], v23.x, y);
    y = fmaf(al[3], v23.y, y);
#pragma unroll
    for (int o = 0; o < 64; ++o)
      acc[o] = fmaf(projw[(o << 6) + ci], y, acc[o]);
  }
  float* op = out + ((size_t)(((bt << 4) + (hd << 2) + c) << 6) << 14) + px;
#pragma unroll
  for (int o = 0; o < 64; ++o) op[(size_t)o << 14] = acc[o];
}

extern "C" void kernel_launch(void* const* d_in, const int* in_sizes, int n_in,
                              void* d_out, int out_size, void* d_ws, size_t ws_size,
                              hipStream_t stream) {
  const float* x = (const float*)d_in[0];
  const float* lnw = (const float*)d_in[1];
  const float* lnb = (const float*)d_in[2];
  const float* qkvw = (const float*)d_in[3];
  const float* dww = (const float*)d_in[4];
  const float* projw = (const float*)d_in[5];
  const float* temp = (const float*)d_in[6];
  float* out = (float*)d_out;

  // workspace (132.1 MiB total):
  //   [0, 128 MiB)   : pre planes (2048 half2 planes for q,k) ; later reused:
  //                    [0,64MiB) v-pre (1024 planes), [64,128MiB) vbuf
  //   [128, 132 MiB) : LN stats (float2 per (bb,px))
  //   [132 MiB, ...) : Sacc (8192 f32) | Nacc (4096) | attn (8192)
  unsigned int* pre = (unsigned int*)d_ws;
  unsigned int* vpre = pre;                              // reused after k_dwqk
  unsigned int* vbuf = pre + ((size_t)1024 << 14);
  float4* stats4 = (float4*)((char*)d_ws + 134217728);
  float* Sacc = (float*)((char*)d_ws + 134217728 + 4194304);
  float* Nacc = Sacc + 8192;
  float* attn = Nacc + 4096;

  hipMemsetAsync(Sacc, 0, (8192 + 4096) * sizeof(float), stream);

  k_stats<<<dim3(1024), dim3(256), 0, stream>>>((const float2*)x, stats4);
  k_pre<16><<<dim3(32, 128), dim3(256), 0, stream>>>((const float2*)x, stats4,
                                                     lnw, lnb, qkvw, pre, 0);
  k_dwqk<<<dim3(32, 128), dim3(256), 0, stream>>>(pre, dww, Sacc, Nacc);
  k_pre<8><<<dim3(32, 128), dim3(256), 0, stream>>>((const float2*)x, stats4,
                                                    lnw, lnb, qkvw, vpre, 32);
  k_dwv<<<dim3(32, 128), dim3(256), 0, stream>>>(vpre, dww, vbuf);
  k_softmax<<<dim3(2), dim3(256), 0, stream>>>(Sacc, Nacc, temp, attn);
  k_outproj<<<dim3(256, 8), dim3(256), 0, stream>>>(vbuf, attn, projw, out);
}

// Round 3
// 327.442 us; speedup vs baseline: 6.5022x; 1.2858x over previous
//
#include <hip/hip_runtime.h>
#include <hip/hip_fp16.h>

__device__ __forceinline__ float2 h2f2(unsigned int u) {
  return __half22float2(__builtin_bit_cast(__half2, u));
}
__device__ __forceinline__ unsigned int f2h2(float a, float b) {
  return __builtin_bit_cast(unsigned int, __floats2half2_rn(a, b));
}

#if __has_builtin(__builtin_amdgcn_fdot2)
typedef _Float16 h2v __attribute__((ext_vector_type(2)));
__device__ __forceinline__ float fdot2(unsigned int a, unsigned int b, float c) {
  return __builtin_amdgcn_fdot2(__builtin_bit_cast(h2v, a),
                                __builtin_bit_cast(h2v, b), c, false);
}
#else
__device__ __forceinline__ float fdot2(unsigned int a, unsigned int b, float c) {
  float2 fa = h2f2(a), fb = h2f2(b);
  return fmaf(fa.y, fb.y, fmaf(fa.x, fb.x, c));
}
#endif

// ---------------- K0: LayerNorm stats per (bb, pixel-pair) ----------------
__global__ __launch_bounds__(256) void k_stats(const float2* __restrict__ x2,
                                               float4* __restrict__ stats4) {
  int id = blockIdx.x * 256 + threadIdx.x;   // 32 * 8192
  int bb = id >> 13;
  int jp = id & 8191;
  const float2* xp = x2 + ((size_t)bb << 19) + jp;
  float s0 = 0.f, q0 = 0.f, s1 = 0.f, q1 = 0.f;
#pragma unroll
  for (int ci = 0; ci < 64; ++ci) {
    float2 v = xp[(size_t)ci << 13];
    s0 += v.x; q0 = fmaf(v.x, v.x, q0);
    s1 += v.y; q1 = fmaf(v.y, v.y, q1);
  }
  float mu0 = s0 * (1.f / 64.f), mu1 = s1 * (1.f / 64.f);
  float4 r;
  r.x = mu0; r.y = rsqrtf(fmaf(-mu0, mu0, q0 * (1.f / 64.f)) + 1e-5f);
  r.z = mu1; r.w = rsqrtf(fmaf(-mu1, mu1, q1 * (1.f / 64.f)) + 1e-5f);
  stats4[id] = r;
}

// ---------------- K1: LN + temporal 1x1 -> fp16 channel-pair planes -------
// grid (32, 128), thread = 2 pixels. First SPLIT pairs -> outA (stride SPLIT
// planes per bc), rest -> outB (stride NO2-SPLIT planes per bc).
template <int NO2, int SPLIT>
__global__ __launch_bounds__(256) void k_pre(
    const float2* __restrict__ x2, const float4* __restrict__ stats4,
    const float* __restrict__ lnw, const float* __restrict__ lnb,
    const float* __restrict__ qkvw, unsigned int* __restrict__ outA,
    unsigned int* __restrict__ outB, int chbase) {
  int bc = blockIdx.y, bt = bc >> 6, ci = bc & 63;
  int jp = blockIdx.x * 256 + threadIdx.x;   // pixel-pair index [0,8192)
  float lw = lnw[ci], lb = lnb[ci];
  float a0[2 * NO2], a1[2 * NO2];
#pragma unroll
  for (int o = 0; o < 2 * NO2; ++o) { a0[o] = 0.f; a1[o] = 0.f; }
#pragma unroll
  for (int t = 0; t < 16; ++t) {
    int bb = (bt << 4) + t;
    float2 xv = x2[(((size_t)bb << 6) + ci) * 8192 + jp];
    float4 st = stats4[((size_t)bb << 13) + jp];
    float xn0 = fmaf((xv.x - st.x) * st.y, lw, lb);
    float xn1 = fmaf((xv.y - st.z) * st.w, lw, lb);
#pragma unroll
    for (int o = 0; o < 2 * NO2; ++o) {
      float w = qkvw[((chbase + o) << 4) + t];
      a0[o] = fmaf(w, xn0, a0[o]);
      a1[o] = fmaf(w, xn1, a1[o]);
    }
  }
#pragma unroll
  for (int o2 = 0; o2 < NO2; ++o2) {
    uint2 st2;
    st2.x = f2h2(a0[2 * o2], a0[2 * o2 + 1]);   // (chEven, chOdd) @ px0
    st2.y = f2h2(a1[2 * o2], a1[2 * o2 + 1]);   // @ px1
    unsigned int* dst;
    if (o2 < SPLIT)
      dst = outA + (((size_t)bc * SPLIT + o2) << 14);
    else
      dst = outB + (((size_t)bc * (NO2 - SPLIT) + (o2 - SPLIT)) << 14);
    *reinterpret_cast<uint2*>(dst + 2 * jp) = st2;
  }
}

// ---------------- K2: dw3x3 on q,k (packed fp16) + attention partials -----
// grid (32, 128, 2): z = head-half. Stages 8 half2 planes (16 channels).
__global__ __launch_bounds__(256) void k_dwqk(
    const unsigned int* __restrict__ pre, const float* __restrict__ dww,
    float* __restrict__ Sacc, float* __restrict__ Nacc) {
  __shared__ unsigned int lds[5040];   // stage [8][630] / later qk [16][272]
  int tid = threadIdx.x;
  int bc = blockIdx.y;
  int zz = blockIdx.z;
  int tx0 = (blockIdx.x & 3) << 5;
  int ty0 = (blockIdx.x >> 2) << 4;
  size_t planeBase = (size_t)bc << 4;
  for (int f = tid; f < 4896; f += 256) {
    int sp = f / 612;
    int r = f - sp * 612;
    int hy = r / 34;
    int hx = r - hy * 34;
    int gp = (sp < 4) ? (4 * zz + sp) : (4 + 4 * zz + sp);  // q / k planes
    int gy = ty0 + hy - 1, gx = tx0 + hx - 1;
    unsigned int val = 0;
    if ((unsigned)gy < 128u && (unsigned)gx < 128u)
      val = pre[((planeBase + gp) << 14) + (gy << 7) + gx];
    lds[sp * 630 + hy * 35 + hx] = val;
  }
  __syncthreads();
  int iy = tid >> 4, jx = tid & 15;
  unsigned int qkw[16];   // (px0,px1) half2 per local channel
#pragma unroll
  for (int sp = 0; sp < 8; ++sp) {
    int gp = (sp < 4) ? (4 * zz + sp) : (4 + 4 * zz + sp);
    const float* wrow = dww + 18 * gp;   // ch 2gp (9 taps), ch 2gp+1 (9 taps)
    __half2 w2[9];
#pragma unroll
    for (int k = 0; k < 9; ++k) w2[k] = __floats2half2_rn(wrow[k], wrow[9 + k]);
    __half2 a0 = __floats2half2_rn(0.f, 0.f), a1 = a0;
    int base = sp * 630 + iy * 35 + 2 * jx;
#pragma unroll
    for (int dy = 0; dy < 3; ++dy) {
      __half2 d0 = __builtin_bit_cast(__half2, lds[base + dy * 35 + 0]);
      __half2 d1 = __builtin_bit_cast(__half2, lds[base + dy * 35 + 1]);
      __half2 d2 = __builtin_bit_cast(__half2, lds[base + dy * 35 + 2]);
      __half2 d3 = __builtin_bit_cast(__half2, lds[base + dy * 35 + 3]);
      a0 = __hfma2(w2[dy * 3 + 0], d0, a0);
      a0 = __hfma2(w2[dy * 3 + 1], d1, a0);
      a0 = __hfma2(w2[dy * 3 + 2], d2, a0);
      a1 = __hfma2(w2[dy * 3 + 0], d1, a1);
      a1 = __hfma2(w2[dy * 3 + 1], d2, a1);
      a1 = __hfma2(w2[dy * 3 + 2], d3, a1);
    }
    unsigned int u0 = __builtin_bit_cast(unsigned int, a0);
    unsigned int u1 = __builtin_bit_cast(unsigned int, a1);
    qkw[2 * sp]     = (u0 & 0xFFFFu) | (u1 << 16);        // chEven: (px0,px1)
    qkw[2 * sp + 1] = (u0 >> 16) | (u1 & 0xFFFF0000u);    // chOdd
  }
  __syncthreads();
#pragma unroll
  for (int r = 0; r < 16; ++r) lds[r * 272 + tid] = qkw[r];
  __syncthreads();
  {  // S partials: 2 heads x 4x4 = 32 combos x 8 px-chunks
    int combo = tid >> 3, pc = tid & 7;
    int hp = combo >> 4, cc = (combo >> 2) & 3, dd = combo & 3;
    const unsigned int* qrow = lds + (hp * 4 + cc) * 272;
    const unsigned int* krow = lds + (8 + hp * 4 + dd) * 272;
    float s = 0.f;
#pragma unroll
    for (int i = 0; i < 32; ++i)
      s = fdot2(qrow[pc + (i << 3)], krow[pc + (i << 3)], s);
    s += __shfl_xor(s, 1); s += __shfl_xor(s, 2); s += __shfl_xor(s, 4);
    if (pc == 0) {
      int hd = 2 * zz + hp;
      atomicAdd(&Sacc[((bc << 2) + hd) * 16 + cc * 4 + dd], s);
    }
  }
  {  // N partials: 16 rows x 16 px-chunks
    int row = tid >> 4, pc = tid & 15;
    const unsigned int* rp = lds + row * 272;
    float n = 0.f;
#pragma unroll
    for (int i = 0; i < 16; ++i)
      n = fdot2(rp[pc + (i << 4)], rp[pc + (i << 4)], n);
    n += __shfl_xor(n, 1); n += __shfl_xor(n, 2);
    n += __shfl_xor(n, 4); n += __shfl_xor(n, 8);
    if (pc == 0) {
      int g = (row < 8) ? (8 * zz + row) : (16 + 8 * zz + (row - 8));
      atomicAdd(&Nacc[(bc << 5) + g], n);
    }
  }
}

// ---------------- K3: dw3x3 on v (packed fp16) -> vbuf --------------------
__global__ __launch_bounds__(256) void k_dwv(
    const unsigned int* __restrict__ pre, const float* __restrict__ dww,
    unsigned int* __restrict__ vbuf) {
  __shared__ unsigned int lds[5040];   // [8][630]
  int tid = threadIdx.x;
  int bc = blockIdx.y;
  int tx0 = (blockIdx.x & 3) << 5;
  int ty0 = (blockIdx.x >> 2) << 4;
  size_t planeBase = (size_t)bc << 3;
  for (int f = tid; f < 4896; f += 256) {
    int sp = f / 612;
    int r = f - sp * 612;
    int hy = r / 34;
    int hx = r - hy * 34;
    int gy = ty0 + hy - 1, gx = tx0 + hx - 1;
    unsigned int val = 0;
    if ((unsigned)gy < 128u && (unsigned)gx < 128u)
      val = pre[((planeBase + sp) << 14) + (gy << 7) + gx];
    lds[sp * 630 + hy * 35 + hx] = val;
  }
  __syncthreads();
  int iy = tid >> 4, jx = tid & 15;
#pragma unroll
  for (int sp = 0; sp < 8; ++sp) {
    const float* wrow = dww + 9 * (32 + 2 * sp);
    __half2 w2[9];
#pragma unroll
    for (int k = 0; k < 9; ++k) w2[k] = __floats2half2_rn(wrow[k], wrow[9 + k]);
    __half2 a0 = __floats2half2_rn(0.f, 0.f), a1 = a0;
    int base = sp * 630 + iy * 35 + 2 * jx;
#pragma unroll
    for (int dy = 0; dy < 3; ++dy) {
      __half2 d0 = __builtin_bit_cast(__half2, lds[base + dy * 35 + 0]);
      __half2 d1 = __builtin_bit_cast(__half2, lds[base + dy * 35 + 1]);
      __half2 d2 = __builtin_bit_cast(__half2, lds[base + dy * 35 + 2]);
      __half2 d3 = __builtin_bit_cast(__half2, lds[base + dy * 35 + 3]);
      a0 = __hfma2(w2[dy * 3 + 0], d0, a0);
      a0 = __hfma2(w2[dy * 3 + 1], d1, a0);
      a0 = __hfma2(w2[dy * 3 + 2], d2, a0);
      a1 = __hfma2(w2[dy * 3 + 0], d1, a1);
      a1 = __hfma2(w2[dy * 3 + 1], d2, a1);
      a1 = __hfma2(w2[dy * 3 + 2], d3, a1);
    }
    uint2 st2;
    st2.x = __builtin_bit_cast(unsigned int, a0);   // (chE,chO)@px0
    st2.y = __builtin_bit_cast(unsigned int, a1);   // @px1
    size_t idx = ((planeBase + sp) << 14) + (size_t)((ty0 + iy) << 7) + tx0 + 2 * jx;
    *reinterpret_cast<uint2*>(vbuf + idx) = st2;
  }
}

// ---------------- K4: 4x4 softmax per (b, head) ----------------
__global__ __launch_bounds__(256) void k_softmax(
    const float* __restrict__ Sacc, const float* __restrict__ Nacc,
    const float* __restrict__ temp, float* __restrict__ attn) {
  int idx = blockIdx.x * 256 + threadIdx.x;
  if (idx >= 512) return;
  int b = idx >> 2, hd = idx & 3;
  float tp = temp[hd];
  float iq[4], ik[4];
#pragma unroll
  for (int c = 0; c < 4; ++c) {
    iq[c] = 1.f / fmaxf(sqrtf(Nacc[(b << 5) + (hd << 2) + c]), 1e-12f);
    ik[c] = 1.f / fmaxf(sqrtf(Nacc[(b << 5) + 16 + (hd << 2) + c]), 1e-12f);
  }
  const float* Sp = Sacc + ((b << 2) + hd) * 16;
  float* ap = attn + ((b << 2) + hd) * 16;
#pragma unroll
  for (int c = 0; c < 4; ++c) {
    float l[4];
#pragma unroll
    for (int d = 0; d < 4; ++d) l[d] = Sp[c * 4 + d] * iq[c] * ik[d] * tp;
    float m = fmaxf(fmaxf(l[0], l[1]), fmaxf(l[2], l[3]));
    float e0 = expf(l[0] - m), e1 = expf(l[1] - m);
    float e2 = expf(l[2] - m), e3 = expf(l[3] - m);
    float inv = 1.f / (e0 + e1 + e2 + e3);
    ap[c * 4 + 0] = e0 * inv;
    ap[c * 4 + 1] = e1 * inv;
    ap[c * 4 + 2] = e2 * inv;
    ap[c * 4 + 3] = e3 * inv;
  }
}

// ---------------- K5: out = proj @ (attn . v), fused ----------------
__global__ __launch_bounds__(256) void k_outproj(
    const unsigned int* __restrict__ vbuf, const float* __restrict__ attn,
    const float* __restrict__ projw, float* __restrict__ out) {
  int bt = blockIdx.y >> 2, hd = blockIdx.y & 3;
  int px = blockIdx.x * 64 + (threadIdx.x & 63);
  int c = threadIdx.x >> 6;   // wave id = temporal row within head

  __shared__ float attn_lds[64 * 16];
  for (int e = threadIdx.x; e < 1024; e += 256) {
    int ci = e >> 4, r = e & 15;
    attn_lds[e] = attn[(((bt * 64 + ci) << 2) + hd) * 16 + r];
  }
  __syncthreads();

  float acc[64];
#pragma unroll
  for (int o = 0; o < 64; ++o) acc[o] = 0.f;

  size_t base = ((((size_t)bt * 64) * 8 + hd * 2) << 14) + px;
  for (int ci = 0; ci < 64; ++ci) {
    size_t off = base + (((size_t)ci * 8) << 14);
    float2 v01 = h2f2(vbuf[off]);
    float2 v23 = h2f2(vbuf[off + (1 << 14)]);
    const float* al = attn_lds + (ci << 4) + (c << 2);   // wave-uniform
    float y = al[0] * v01.x;
    y = fmaf(al[1], v01.y, y);
    y = fmaf(al[2], v23.x, y);
    y = fmaf(al[3], v23.y, y);
#pragma unroll
    for (int o = 0; o < 64; ++o)
      acc[o] = fmaf(projw[(o << 6) + ci], y, acc[o]);
  }
  float* op = out + ((size_t)(((bt << 4) + (hd << 2) + c) << 6) << 14) + px;
#pragma unroll
  for (int o = 0; o < 64; ++o) op[(size_t)o << 14] = acc[o];
}

extern "C" void kernel_launch(void* const* d_in, const int* in_sizes, int n_in,
                              void* d_out, int out_size, void* d_ws, size_t ws_size,
                              hipStream_t stream) {
  const float* x = (const float*)d_in[0];
  const float* lnw = (const float*)d_in[1];
  const float* lnb = (const float*)d_in[2];
  const float* qkvw = (const float*)d_in[3];
  const float* dww = (const float*)d_in[4];
  const float* projw = (const float*)d_in[5];
  const float* temp = (const float*)d_in[6];
  float* out = (float*)d_out;

  // Big path (needs 196.1 MiB): segA qk-pre [0,128Mi), segB v-pre [128,192Mi),
  // stats @192Mi, accums after; vbuf reuses segA[0,64Mi).
  const size_t NEED_BIG = 134217728ull + 67108864ull + 4194304ull + 81920ull;
  unsigned int* ws = (unsigned int*)d_ws;

  if (ws_size >= NEED_BIG) {
    unsigned int* segA = ws;
    unsigned int* segB = ws + ((size_t)134217728 / 4);
    float4* stats4 = (float4*)((char*)d_ws + 201326592ull);
    float* Sacc = (float*)((char*)d_ws + 201326592ull + 4194304ull);
    float* Nacc = Sacc + 8192;
    float* attn = Nacc + 4096;
    unsigned int* vbuf = segA;   // overwritten after k_dwqk consumed segA

    hipMemsetAsync(Sacc, 0, (8192 + 4096) * sizeof(float), stream);
    k_stats<<<dim3(1024), dim3(256), 0, stream>>>((const float2*)x, stats4);
    k_pre<24, 16><<<dim3(32, 128), dim3(256), 0, stream>>>(
        (const float2*)x, stats4, lnw, lnb, qkvw, segA, segB, 0);
    k_dwqk<<<dim3(32, 128, 2), dim3(256), 0, stream>>>(segA, dww, Sacc, Nacc);
    k_dwv<<<dim3(32, 128), dim3(256), 0, stream>>>(segB, dww, vbuf);
    k_softmax<<<dim3(2), dim3(256), 0, stream>>>(Sacc, Nacc, temp, attn);
    k_outproj<<<dim3(256, 8), dim3(256), 0, stream>>>(vbuf, attn, projw, out);
  } else {
    // Fallback: two-pass pre (proven 138.5 MiB layout)
    unsigned int* pre = ws;
    unsigned int* vpre = pre;                        // reused after k_dwqk
    unsigned int* vbuf = pre + ((size_t)1024 << 14); // [64,128) MiB
    float4* stats4 = (float4*)((char*)d_ws + 134217728ull);
    float* Sacc = (float*)((char*)d_ws + 134217728ull + 4194304ull);
    float* Nacc = Sacc + 8192;
    float* attn = Nacc + 4096;

    hipMemsetAsync(Sacc, 0, (8192 + 4096) * sizeof(float), stream);
    k_stats<<<dim3(1024), dim3(256), 0, stream>>>((const float2*)x, stats4);
    k_pre<16, 16><<<dim3(32, 128), dim3(256), 0, stream>>>(
        (const float2*)x, stats4, lnw, lnb, qkvw, pre, nullptr, 0);
    k_dwqk<<<dim3(32, 128, 2), dim3(256), 0, stream>>>(pre, dww, Sacc, Nacc);
    k_pre<8, 8><<<dim3(32, 128), dim3(256), 0, stream>>>(
        (const float2*)x, stats4, lnw, lnb, qkvw, vpre, nullptr, 32);
    k_dwv<<<dim3(32, 128), dim3(256), 0, stream>>>(vpre, dww, vbuf);
    k_softmax<<<dim3(2), dim3(256), 0, stream>>>(Sacc, Nacc, temp, attn);
    k_outproj<<<dim3(256, 8), dim3(256), 0, stream>>>(vbuf, attn, projw, out);
  }
}

// Round 4
// 302.677 us; speedup vs baseline: 7.0343x; 1.0818x over previous
//
#include <hip/hip_runtime.h>
#include <hip/hip_fp16.h>

__device__ __forceinline__ float2 h2f2(unsigned int u) {
  return __half22float2(__builtin_bit_cast(__half2, u));
}
__device__ __forceinline__ unsigned int f2h2(float a, float b) {
  return __builtin_bit_cast(unsigned int, __floats2half2_rn(a, b));
}

#if __has_builtin(__builtin_amdgcn_fdot2)
typedef _Float16 h2v __attribute__((ext_vector_type(2)));
__device__ __forceinline__ float fdot2(unsigned int a, unsigned int b, float c) {
  return __builtin_amdgcn_fdot2(__builtin_bit_cast(h2v, a),
                                __builtin_bit_cast(h2v, b), c, false);
}
#else
__device__ __forceinline__ float fdot2(unsigned int a, unsigned int b, float c) {
  float2 fa = h2f2(a), fb = h2f2(b);
  return fmaf(fa.y, fb.y, fmaf(fa.x, fb.x, c));
}
#endif

// ---------------- K0: LayerNorm stats per (bb, pixel-pair) ----------------
__global__ __launch_bounds__(256) void k_stats(const float2* __restrict__ x2,
                                               float4* __restrict__ stats4) {
  int id = blockIdx.x * 256 + threadIdx.x;   // 32 * 8192
  int bb = id >> 13;
  int jp = id & 8191;
  const float2* xp = x2 + ((size_t)bb << 19) + jp;
  float s0 = 0.f, q0 = 0.f, s1 = 0.f, q1 = 0.f;
#pragma unroll
  for (int ci = 0; ci < 64; ++ci) {
    float2 v = xp[(size_t)ci << 13];
    s0 += v.x; q0 = fmaf(v.x, v.x, q0);
    s1 += v.y; q1 = fmaf(v.y, v.y, q1);
  }
  float mu0 = s0 * (1.f / 64.f), mu1 = s1 * (1.f / 64.f);
  float4 r;
  r.x = mu0; r.y = rsqrtf(fmaf(-mu0, mu0, q0 * (1.f / 64.f)) + 1e-5f);
  r.z = mu1; r.w = rsqrtf(fmaf(-mu1, mu1, q1 * (1.f / 64.f)) + 1e-5f);
  stats4[id] = r;
}

// ---------------- K1: LN + temporal 1x1 -> fp16 channel-pair planes -------
template <int NO2, int SPLIT>
__global__ __launch_bounds__(256) void k_pre(
    const float2* __restrict__ x2, const float4* __restrict__ stats4,
    const float* __restrict__ lnw, const float* __restrict__ lnb,
    const float* __restrict__ qkvw, unsigned int* __restrict__ outA,
    unsigned int* __restrict__ outB, int chbase) {
  int bc = blockIdx.y, bt = bc >> 6, ci = bc & 63;
  int jp = blockIdx.x * 256 + threadIdx.x;   // pixel-pair index [0,8192)
  float lw = lnw[ci], lb = lnb[ci];
  float a0[2 * NO2], a1[2 * NO2];
#pragma unroll
  for (int o = 0; o < 2 * NO2; ++o) { a0[o] = 0.f; a1[o] = 0.f; }
#pragma unroll
  for (int t = 0; t < 16; ++t) {
    int bb = (bt << 4) + t;
    float2 xv = x2[(((size_t)bb << 6) + ci) * 8192 + jp];
    float4 st = stats4[((size_t)bb << 13) + jp];
    float xn0 = fmaf((xv.x - st.x) * st.y, lw, lb);
    float xn1 = fmaf((xv.y - st.z) * st.w, lw, lb);
#pragma unroll
    for (int o = 0; o < 2 * NO2; ++o) {
      float w = qkvw[((chbase + o) << 4) + t];
      a0[o] = fmaf(w, xn0, a0[o]);
      a1[o] = fmaf(w, xn1, a1[o]);
    }
  }
#pragma unroll
  for (int o2 = 0; o2 < NO2; ++o2) {
    uint2 st2;
    st2.x = f2h2(a0[2 * o2], a0[2 * o2 + 1]);   // (chEven, chOdd) @ px0
    st2.y = f2h2(a1[2 * o2], a1[2 * o2 + 1]);   // @ px1
    unsigned int* dst;
    if (o2 < SPLIT)
      dst = outA + (((size_t)bc * SPLIT + o2) << 14);
    else
      dst = outB + (((size_t)bc * (NO2 - SPLIT) + (o2 - SPLIT)) << 14);
    *reinterpret_cast<uint2*>(dst + 2 * jp) = st2;
  }
}

// ---------------- K2: dw3x3 on q,k (packed fp16) + attention partials -----
__global__ __launch_bounds__(256) void k_dwqk(
    const unsigned int* __restrict__ pre, const float* __restrict__ dww,
    float* __restrict__ Sacc, float* __restrict__ Nacc) {
  __shared__ unsigned int lds[5040];   // stage [8][630] / later qk [16][272]
  int tid = threadIdx.x;
  int bc = blockIdx.y;
  int zz = blockIdx.z;
  int tx0 = (blockIdx.x & 3) << 5;
  int ty0 = (blockIdx.x >> 2) << 4;
  size_t planeBase = (size_t)bc << 4;
  for (int f = tid; f < 4896; f += 256) {
    int sp = f / 612;
    int r = f - sp * 612;
    int hy = r / 34;
    int hx = r - hy * 34;
    int gp = (sp < 4) ? (4 * zz + sp) : (4 + 4 * zz + sp);  // q / k planes
    int gy = ty0 + hy - 1, gx = tx0 + hx - 1;
    unsigned int val = 0;
    if ((unsigned)gy < 128u && (unsigned)gx < 128u)
      val = pre[((planeBase + gp) << 14) + (gy << 7) + gx];
    lds[sp * 630 + hy * 35 + hx] = val;
  }
  __syncthreads();
  int iy = tid >> 4, jx = tid & 15;
  unsigned int qkw[16];   // (px0,px1) half2 per local channel
#pragma unroll
  for (int sp = 0; sp < 8; ++sp) {
    int gp = (sp < 4) ? (4 * zz + sp) : (4 + 4 * zz + sp);
    const float* wrow = dww + 18 * gp;
    __half2 w2[9];
#pragma unroll
    for (int k = 0; k < 9; ++k) w2[k] = __floats2half2_rn(wrow[k], wrow[9 + k]);
    __half2 a0 = __floats2half2_rn(0.f, 0.f), a1 = a0;
    int base = sp * 630 + iy * 35 + 2 * jx;
#pragma unroll
    for (int dy = 0; dy < 3; ++dy) {
      __half2 d0 = __builtin_bit_cast(__half2, lds[base + dy * 35 + 0]);
      __half2 d1 = __builtin_bit_cast(__half2, lds[base + dy * 35 + 1]);
      __half2 d2 = __builtin_bit_cast(__half2, lds[base + dy * 35 + 2]);
      __half2 d3 = __builtin_bit_cast(__half2, lds[base + dy * 35 + 3]);
      a0 = __hfma2(w2[dy * 3 + 0], d0, a0);
      a0 = __hfma2(w2[dy * 3 + 1], d1, a0);
      a0 = __hfma2(w2[dy * 3 + 2], d2, a0);
      a1 = __hfma2(w2[dy * 3 + 0], d1, a1);
      a1 = __hfma2(w2[dy * 3 + 1], d2, a1);
      a1 = __hfma2(w2[dy * 3 + 2], d3, a1);
    }
    unsigned int u0 = __builtin_bit_cast(unsigned int, a0);
    unsigned int u1 = __builtin_bit_cast(unsigned int, a1);
    qkw[2 * sp]     = (u0 & 0xFFFFu) | (u1 << 16);        // chEven: (px0,px1)
    qkw[2 * sp + 1] = (u0 >> 16) | (u1 & 0xFFFF0000u);    // chOdd
  }
  __syncthreads();
#pragma unroll
  for (int r = 0; r < 16; ++r) lds[r * 272 + tid] = qkw[r];
  __syncthreads();
  {  // S partials: 2 heads x 4x4 = 32 combos x 8 px-chunks
    int combo = tid >> 3, pc = tid & 7;
    int hp = combo >> 4, cc = (combo >> 2) & 3, dd = combo & 3;
    const unsigned int* qrow = lds + (hp * 4 + cc) * 272;
    const unsigned int* krow = lds + (8 + hp * 4 + dd) * 272;
    float s = 0.f;
#pragma unroll
    for (int i = 0; i < 32; ++i)
      s = fdot2(qrow[pc + (i << 3)], krow[pc + (i << 3)], s);
    s += __shfl_xor(s, 1); s += __shfl_xor(s, 2); s += __shfl_xor(s, 4);
    if (pc == 0) {
      int hd = 2 * zz + hp;
      atomicAdd(&Sacc[((bc << 2) + hd) * 16 + cc * 4 + dd], s);
    }
  }
  {  // N partials: 16 rows x 16 px-chunks
    int row = tid >> 4, pc = tid & 15;
    const unsigned int* rp = lds + row * 272;
    float n = 0.f;
#pragma unroll
    for (int i = 0; i < 16; ++i)
      n = fdot2(rp[pc + (i << 4)], rp[pc + (i << 4)], n);
    n += __shfl_xor(n, 1); n += __shfl_xor(n, 2);
    n += __shfl_xor(n, 4); n += __shfl_xor(n, 8);
    if (pc == 0) {
      int g = (row < 8) ? (8 * zz + row) : (16 + 8 * zz + (row - 8));
      atomicAdd(&Nacc[(bc << 5) + g], n);
    }
  }
}

// ---------------- K3: dw3x3 on v (packed fp16) -> vbuf --------------------
__global__ __launch_bounds__(256) void k_dwv(
    const unsigned int* __restrict__ pre, const float* __restrict__ dww,
    unsigned int* __restrict__ vbuf) {
  __shared__ unsigned int lds[5040];   // [8][630]
  int tid = threadIdx.x;
  int bc = blockIdx.y;
  int tx0 = (blockIdx.x & 3) << 5;
  int ty0 = (blockIdx.x >> 2) << 4;
  size_t planeBase = (size_t)bc << 3;
  for (int f = tid; f < 4896; f += 256) {
    int sp = f / 612;
    int r = f - sp * 612;
    int hy = r / 34;
    int hx = r - hy * 34;
    int gy = ty0 + hy - 1, gx = tx0 + hx - 1;
    unsigned int val = 0;
    if ((unsigned)gy < 128u && (unsigned)gx < 128u)
      val = pre[((planeBase + sp) << 14) + (gy << 7) + gx];
    lds[sp * 630 + hy * 35 + hx] = val;
  }
  __syncthreads();
  int iy = tid >> 4, jx = tid & 15;
#pragma unroll
  for (int sp = 0; sp < 8; ++sp) {
    const float* wrow = dww + 9 * (32 + 2 * sp);
    __half2 w2[9];
#pragma unroll
    for (int k = 0; k < 9; ++k) w2[k] = __floats2half2_rn(wrow[k], wrow[9 + k]);
    __half2 a0 = __floats2half2_rn(0.f, 0.f), a1 = a0;
    int base = sp * 630 + iy * 35 + 2 * jx;
#pragma unroll
    for (int dy = 0; dy < 3; ++dy) {
      __half2 d0 = __builtin_bit_cast(__half2, lds[base + dy * 35 + 0]);
      __half2 d1 = __builtin_bit_cast(__half2, lds[base + dy * 35 + 1]);
      __half2 d2 = __builtin_bit_cast(__half2, lds[base + dy * 35 + 2]);
      __half2 d3 = __builtin_bit_cast(__half2, lds[base + dy * 35 + 3]);
      a0 = __hfma2(w2[dy * 3 + 0], d0, a0);
      a0 = __hfma2(w2[dy * 3 + 1], d1, a0);
      a0 = __hfma2(w2[dy * 3 + 2], d2, a0);
      a1 = __hfma2(w2[dy * 3 + 0], d1, a1);
      a1 = __hfma2(w2[dy * 3 + 1], d2, a1);
      a1 = __hfma2(w2[dy * 3 + 2], d3, a1);
    }
    uint2 st2;
    st2.x = __builtin_bit_cast(unsigned int, a0);
    st2.y = __builtin_bit_cast(unsigned int, a1);
    size_t idx = ((planeBase + sp) << 14) + (size_t)((ty0 + iy) << 7) + tx0 + 2 * jx;
    *reinterpret_cast<uint2*>(vbuf + idx) = st2;
  }
}

// ---------------- K4: softmax -> packed fp16 attention rows ----------------
__global__ __launch_bounds__(256) void k_softmax(
    const float* __restrict__ Sacc, const float* __restrict__ Nacc,
    const float* __restrict__ temp, unsigned int* __restrict__ attnpk) {
  int idx = blockIdx.x * 256 + threadIdx.x;
  if (idx >= 512) return;
  int b = idx >> 2, hd = idx & 3;   // b = bt*64 + ci
  int bt = b >> 6, ci = b & 63;
  float tp = temp[hd];
  float iq[4], ik[4];
#pragma unroll
  for (int c = 0; c < 4; ++c) {
    iq[c] = 1.f / fmaxf(sqrtf(Nacc[(b << 5) + (hd << 2) + c]), 1e-12f);
    ik[c] = 1.f / fmaxf(sqrtf(Nacc[(b << 5) + 16 + (hd << 2) + c]), 1e-12f);
  }
  const float* Sp = Sacc + ((b << 2) + hd) * 16;
#pragma unroll
  for (int c = 0; c < 4; ++c) {
    float l[4];
#pragma unroll
    for (int d = 0; d < 4; ++d) l[d] = Sp[c * 4 + d] * iq[c] * ik[d] * tp;
    float m = fmaxf(fmaxf(l[0], l[1]), fmaxf(l[2], l[3]));
    float e0 = expf(l[0] - m), e1 = expf(l[1] - m);
    float e2 = expf(l[2] - m), e3 = expf(l[3] - m);
    float inv = 1.f / (e0 + e1 + e2 + e3);
    // packed rows for k_outproj: [bt][hd][c][ci][2]
    unsigned int* dst = attnpk + ((((bt * 4 + hd) * 4 + c) << 7) + ci * 2);
    dst[0] = f2h2(e0 * inv, e1 * inv);
    dst[1] = f2h2(e2 * inv, e3 * inv);
  }
}

// ---------------- K4b: pack projw to half2 [o][ci2] ----------------
__global__ __launch_bounds__(256) void k_projpack(const float* __restrict__ projw,
                                                  unsigned int* __restrict__ projpk) {
  int idx = blockIdx.x * 256 + threadIdx.x;   // 2048
  if (idx >= 2048) return;
  int o = idx >> 5, ci2 = idx & 31;
  projpk[idx] = f2h2(projw[(o << 6) + 2 * ci2], projw[(o << 6) + 2 * ci2 + 1]);
}

// ---------------- K5: out = proj @ (attn . v) via packed dot2 ----------------
// grid (64 strips of 256px, 32 = bt*16 + cr); thread = 1 px; acc[64] in VGPRs.
__global__ __launch_bounds__(256) void k_outproj(
    const unsigned int* __restrict__ vbuf, const unsigned int* __restrict__ attnpk,
    const unsigned int* __restrict__ projpk, float* __restrict__ out) {
  int comb = blockIdx.y;                 // bt*16 + hd*4 + c
  int bt = comb >> 4, hd = (comb >> 2) & 3, c = comb & 3;
  int px = (blockIdx.x << 8) + threadIdx.x;

  const unsigned int* apk = attnpk + (((bt * 4 + hd) * 4 + c) << 7);  // uniform
  float acc[64];
#pragma unroll
  for (int o = 0; o < 64; ++o) acc[o] = 0.f;

  size_t vbase = ((((size_t)bt * 512) + hd * 2) << 14) + px;   // (bt*64ci)*8 planes
  for (int ci2 = 0; ci2 < 32; ++ci2) {
    size_t off0 = vbase + (((size_t)(2 * ci2) * 8) << 14);
    size_t off1 = off0 + ((size_t)8 << 14);
    unsigned int v0a = vbuf[off0];
    unsigned int v0b = vbuf[off0 + (1 << 14)];
    unsigned int v1a = vbuf[off1];
    unsigned int v1b = vbuf[off1 + (1 << 14)];
    float y0 = fdot2(v0a, apk[4 * ci2 + 0], fdot2(v0b, apk[4 * ci2 + 1], 0.f));
    float y1 = fdot2(v1a, apk[4 * ci2 + 2], fdot2(v1b, apk[4 * ci2 + 3], 0.f));
    unsigned int y2 = f2h2(y0, y1);
#pragma unroll
    for (int o = 0; o < 64; ++o)
      acc[o] = fdot2(y2, projpk[(o << 5) + ci2], acc[o]);   // SGPR-fed dot2
  }
  float* op = out + (((size_t)comb << 6) << 14) + px;
#pragma unroll
  for (int o = 0; o < 64; ++o) op[(size_t)o << 14] = acc[o];
}

extern "C" void kernel_launch(void* const* d_in, const int* in_sizes, int n_in,
                              void* d_out, int out_size, void* d_ws, size_t ws_size,
                              hipStream_t stream) {
  const float* x = (const float*)d_in[0];
  const float* lnw = (const float*)d_in[1];
  const float* lnb = (const float*)d_in[2];
  const float* qkvw = (const float*)d_in[3];
  const float* dww = (const float*)d_in[4];
  const float* projw = (const float*)d_in[5];
  const float* temp = (const float*)d_in[6];
  float* out = (float*)d_out;

  const size_t TAIL = 4194304ull + 49152ull + 8192ull + 16384ull;  // stats+acc+packs
  const size_t NEED_BIG = 134217728ull + 67108864ull + TAIL;
  unsigned int* ws = (unsigned int*)d_ws;

  if (ws_size >= NEED_BIG) {
    // segA qk-pre [0,128Mi), segB v-pre [128,192Mi), tail after; vbuf reuses segA.
    unsigned int* segA = ws;
    unsigned int* segB = ws + (134217728ull / 4);
    char* tail = (char*)d_ws + 201326592ull;
    float4* stats4 = (float4*)tail;
    float* Sacc = (float*)(tail + 4194304ull);
    float* Nacc = Sacc + 8192;                     // +32 KB
    unsigned int* projpk = (unsigned int*)(Nacc + 4096);  // +16 KB
    unsigned int* attnpk = projpk + 2048;          // +8 KB
    unsigned int* vbuf = segA;

    hipMemsetAsync(Sacc, 0, (8192 + 4096) * sizeof(float), stream);
    k_stats<<<dim3(1024), dim3(256), 0, stream>>>((const float2*)x, stats4);
    k_projpack<<<dim3(8), dim3(256), 0, stream>>>(projw, projpk);
    k_pre<24, 16><<<dim3(32, 128), dim3(256), 0, stream>>>(
        (const float2*)x, stats4, lnw, lnb, qkvw, segA, segB, 0);
    k_dwqk<<<dim3(32, 128, 2), dim3(256), 0, stream>>>(segA, dww, Sacc, Nacc);
    k_dwv<<<dim3(32, 128), dim3(256), 0, stream>>>(segB, dww, vbuf);
    k_softmax<<<dim3(2), dim3(256), 0, stream>>>(Sacc, Nacc, temp, attnpk);
    k_outproj<<<dim3(64, 32), dim3(256), 0, stream>>>(vbuf, attnpk, projpk, out);
  } else {
    // Fallback: two-pass pre (138.6 MiB layout)
    unsigned int* pre = ws;
    unsigned int* vpre = pre;                        // reused after k_dwqk
    unsigned int* vbuf = pre + ((size_t)1024 << 14); // [64,128) MiB
    char* tail = (char*)d_ws + 134217728ull;
    float4* stats4 = (float4*)tail;
    float* Sacc = (float*)(tail + 4194304ull);
    float* Nacc = Sacc + 8192;
    unsigned int* projpk = (unsigned int*)(Nacc + 4096);
    unsigned int* attnpk = projpk + 2048;

    hipMemsetAsync(Sacc, 0, (8192 + 4096) * sizeof(float), stream);
    k_stats<<<dim3(1024), dim3(256), 0, stream>>>((const float2*)x, stats4);
    k_projpack<<<dim3(8), dim3(256), 0, stream>>>(projw, projpk);
    k_pre<16, 16><<<dim3(32, 128), dim3(256), 0, stream>>>(
        (const float2*)x, stats4, lnw, lnb, qkvw, pre, nullptr, 0);
    k_dwqk<<<dim3(32, 128, 2), dim3(256), 0, stream>>>(pre, dww, Sacc, Nacc);
    k_pre<8, 8><<<dim3(32, 128), dim3(256), 0, stream>>>(
        (const float2*)x, stats4, lnw, lnb, qkvw, vpre, nullptr, 32);
    k_dwv<<<dim3(32, 128), dim3(256), 0, stream>>>(vpre, dww, vbuf);
    k_softmax<<<dim3(2), dim3(256), 0, stream>>>(Sacc, Nacc, temp, attnpk);
    k_outproj<<<dim3(64, 32), dim3(256), 0, stream>>>(vbuf, attnpk, projpk, out);
  }
}

// Round 5
// 207.173 us; speedup vs baseline: 10.2769x; 1.4610x over previous
//
#include <hip/hip_runtime.h>
#include <hip/hip_fp16.h>

__device__ __forceinline__ float2 h2f2(unsigned int u) {
  return __half22float2(__builtin_bit_cast(__half2, u));
}
__device__ __forceinline__ unsigned int f2h2(float a, float b) {
  return __builtin_bit_cast(unsigned int, __floats2half2_rn(a, b));
}

#if __has_builtin(__builtin_amdgcn_fdot2)
typedef _Float16 h2v __attribute__((ext_vector_type(2)));
__device__ __forceinline__ float fdot2(unsigned int a, unsigned int b, float c) {
  return __builtin_amdgcn_fdot2(__builtin_bit_cast(h2v, a),
                                __builtin_bit_cast(h2v, b), c, false);
}
#else
__device__ __forceinline__ float fdot2(unsigned int a, unsigned int b, float c) {
  float2 fa = h2f2(a), fb = h2f2(b);
  return fmaf(fa.y, fb.y, fmaf(fa.x, fb.x, c));
}
#endif

// ---------------- K0: LayerNorm stats per (bb, pixel-pair) ----------------
__global__ __launch_bounds__(256) void k_stats(const float2* __restrict__ x2,
                                               float4* __restrict__ stats4) {
  int id = blockIdx.x * 256 + threadIdx.x;   // 32 * 8192
  int bb = id >> 13;
  int jp = id & 8191;
  const float2* xp = x2 + ((size_t)bb << 19) + jp;
  float s0 = 0.f, q0 = 0.f, s1 = 0.f, q1 = 0.f;
#pragma unroll
  for (int ci = 0; ci < 64; ++ci) {
    float2 v = xp[(size_t)ci << 13];
    s0 += v.x; q0 = fmaf(v.x, v.x, q0);
    s1 += v.y; q1 = fmaf(v.y, v.y, q1);
  }
  float mu0 = s0 * (1.f / 64.f), mu1 = s1 * (1.f / 64.f);
  float4 r;
  r.x = mu0; r.y = rsqrtf(fmaf(-mu0, mu0, q0 * (1.f / 64.f)) + 1e-5f);
  r.z = mu1; r.w = rsqrtf(fmaf(-mu1, mu1, q1 * (1.f / 64.f)) + 1e-5f);
  stats4[id] = r;
}

// ---------------- K0b: pack all weights to half2 ----------------
// projpk[2048]: [o][ci2]; qkvpk[384]: [ch48][tp8] = (w[ch][2tp],w[ch][2tp+1]);
// dwpk[216]: [pl24][k9] = (dww[2pl][k], dww[2pl+1][k])
__global__ __launch_bounds__(256) void k_wpack(
    const float* __restrict__ qkvw, const float* __restrict__ dww,
    const float* __restrict__ projw, unsigned int* __restrict__ qkvpk,
    unsigned int* __restrict__ dwpk, unsigned int* __restrict__ projpk) {
  int t = blockIdx.x * 256 + threadIdx.x;
  if (t < 2048) {
    int o = t >> 5, c2 = t & 31;
    projpk[t] = f2h2(projw[(o << 6) + 2 * c2], projw[(o << 6) + 2 * c2 + 1]);
  } else if (t < 2432) {
    int i = t - 2048;
    int ch = i >> 3, tp = i & 7;
    qkvpk[i] = f2h2(qkvw[(ch << 4) + 2 * tp], qkvw[(ch << 4) + 2 * tp + 1]);
  } else if (t < 2648) {
    int i = t - 2432;
    int pl = i / 9, k = i - pl * 9;
    dwpk[i] = f2h2(dww[18 * pl + k], dww[18 * pl + 9 + k]);
  }
}

// ---------------- K1: fused LN + 1x1(16->48) + dw3x3 + attn partials + v ----
// grid (32 tiles of 32x16, 128 = bt*64+ci), block 256, thread = 2 px + 3 halo pos
__global__ __launch_bounds__(256) void k_fused(
    const float* __restrict__ x, const float2* __restrict__ stats2,
    const float* __restrict__ lnw, const float* __restrict__ lnb,
    const unsigned int* __restrict__ qkvpk, const unsigned int* __restrict__ dwpk,
    unsigned int* __restrict__ vbuf, float* __restrict__ Sacc,
    float* __restrict__ Nacc) {
  __shared__ unsigned int pre[2520];   // 4 planes x [18][35]; aliased qk[8][272]
  int tid = threadIdx.x;
  int bc = blockIdx.y, bt = bc >> 6, ci = bc & 63;
  int tx0 = (blockIdx.x & 3) << 5, ty0 = (blockIdx.x >> 2) << 4;
  float lw = lnw[ci], lb = lnb[ci];

  // ---- stage: LN'd x as (t, t+1) half2, registers only. pos = tid + 256*it
  unsigned int wc[3][8];
  int waddr[3];   // pre write offset hy*35+hx, or -1 inactive
  {
    size_t xci = ((size_t)(bt * 1024 + ci)) << 14;
    int sbase = bt << 18;   // bt*16*16384
#pragma unroll
    for (int it = 0; it < 3; ++it) {
      int pos = tid + (it << 8);
      bool act = pos < 612;
      int hy = pos / 34, hx = pos - hy * 34;
      int gy = ty0 + hy - 1, gx = tx0 + hx - 1;
      bool ok = act && ((unsigned)gy < 128u) && ((unsigned)gx < 128u);
      waddr[it] = act ? (hy * 35 + hx) : -1;
      int gp = (gy << 7) + gx;
#pragma unroll
      for (int tp = 0; tp < 8; ++tp) {
        unsigned int w = 0;
        if (ok) {
          float x0 = x[xci + ((size_t)(2 * tp) << 20) + gp];
          float x1 = x[xci + ((size_t)(2 * tp + 1) << 20) + gp];
          float2 s0 = stats2[sbase + (2 * tp) * 16384 + gp];
          float2 s1 = stats2[sbase + (2 * tp + 1) * 16384 + gp];
          w = f2h2(fmaf((x0 - s0.x) * s0.y, lw, lb),
                   fmaf((x1 - s1.x) * s1.y, lw, lb));
        }
        wc[it][tp] = w;
      }
    }
  }

  int iy = tid >> 4, jx = tid & 15;
  int dwbase = iy * 35 + 2 * jx;

  // ---- head chunks: h = 0..3 -> planes {2h,2h+1, 8+2h,8+2h+1}
  for (int h = 0; h < 4; ++h) {
    // 1x1 into pre (f32 accum via dot2 over t-pairs)
#pragma unroll
    for (int it = 0; it < 3; ++it) {
      if (waddr[it] >= 0) {
        float acc[8];
#pragma unroll
        for (int c = 0; c < 8; ++c) {
          int gch = (c < 4) ? (4 * h + c) : (16 + 4 * h + (c - 4));
          float s = 0.f;
#pragma unroll
          for (int tp = 0; tp < 8; ++tp)
            s = fdot2(wc[it][tp], qkvpk[gch * 8 + tp], s);
          acc[c] = s;
        }
#pragma unroll
        for (int pl = 0; pl < 4; ++pl)
          pre[pl * 630 + waddr[it]] = f2h2(acc[2 * pl], acc[2 * pl + 1]);
      }
    }
    __syncthreads();
    // dw 3x3 (packed fp16), output (px0,px1) per channel
    unsigned int qkw[8];
#pragma unroll
    for (int pl = 0; pl < 4; ++pl) {
      int gpl = (pl < 2) ? (2 * h + pl) : (8 + 2 * h + (pl - 2));
      const unsigned int* wp = dwpk + gpl * 9;
      __half2 a0 = __floats2half2_rn(0.f, 0.f), a1 = a0;
      int base = pl * 630 + dwbase;
#pragma unroll
      for (int dy = 0; dy < 3; ++dy) {
        __half2 d0 = __builtin_bit_cast(__half2, pre[base + dy * 35 + 0]);
        __half2 d1 = __builtin_bit_cast(__half2, pre[base + dy * 35 + 1]);
        __half2 d2 = __builtin_bit_cast(__half2, pre[base + dy * 35 + 2]);
        __half2 d3 = __builtin_bit_cast(__half2, pre[base + dy * 35 + 3]);
        __half2 w0 = __builtin_bit_cast(__half2, wp[dy * 3 + 0]);
        __half2 w1 = __builtin_bit_cast(__half2, wp[dy * 3 + 1]);
        __half2 w2 = __builtin_bit_cast(__half2, wp[dy * 3 + 2]);
        a0 = __hfma2(w0, d0, a0); a0 = __hfma2(w1, d1, a0); a0 = __hfma2(w2, d2, a0);
        a1 = __hfma2(w0, d1, a1); a1 = __hfma2(w1, d2, a1); a1 = __hfma2(w2, d3, a1);
      }
      unsigned int u0 = __builtin_bit_cast(unsigned int, a0);
      unsigned int u1 = __builtin_bit_cast(unsigned int, a1);
      qkw[2 * pl]     = (u0 & 0xFFFFu) | (u1 << 16);
      qkw[2 * pl + 1] = (u0 >> 16) | (u1 & 0xFFFF0000u);
    }
    __syncthreads();   // pre reads done; safe to alias
#pragma unroll
    for (int r = 0; r < 8; ++r) pre[r * 272 + tid] = qkw[r];
    __syncthreads();
    {  // S partials: 16 combos x 16 px-chunks
      int cd = tid >> 4, pc = tid & 15;
      int cc = cd >> 2, dd = cd & 3;
      const unsigned int* qrow = pre + cc * 272;
      const unsigned int* krow = pre + (4 + dd) * 272;
      float s = 0.f;
#pragma unroll
      for (int i = 0; i < 16; ++i)
        s = fdot2(qrow[pc + (i << 4)], krow[pc + (i << 4)], s);
      s += __shfl_xor(s, 1); s += __shfl_xor(s, 2);
      s += __shfl_xor(s, 4); s += __shfl_xor(s, 8);
      if (pc == 0) atomicAdd(&Sacc[((bc << 2) + h) * 16 + cc * 4 + dd], s);
    }
    {  // N partials: 8 rows x 32 px-chunks
      int row = tid >> 5, pc = tid & 31;
      const unsigned int* rp = pre + row * 272;
      float n = 0.f;
#pragma unroll
      for (int i = 0; i < 8; ++i) {
        unsigned int v = rp[pc + (i << 5)];
        n = fdot2(v, v, n);
      }
      n += __shfl_xor(n, 1); n += __shfl_xor(n, 2); n += __shfl_xor(n, 4);
      n += __shfl_xor(n, 8); n += __shfl_xor(n, 16);
      if (pc == 0) {
        int g = (row < 4) ? (4 * h + row) : (16 + 4 * h + (row - 4));
        atomicAdd(&Nacc[(bc << 5) + g], n);
      }
    }
    __syncthreads();   // qk reads done before next chunk's 1x1 writes
  }

  // ---- v chunks: vc = 0,1 -> planes 16+4vc .. 19+4vc (v ch 8vc..8vc+7)
  for (int vc = 0; vc < 2; ++vc) {
#pragma unroll
    for (int it = 0; it < 3; ++it) {
      if (waddr[it] >= 0) {
        float acc[8];
#pragma unroll
        for (int c = 0; c < 8; ++c) {
          int gch = 32 + 8 * vc + c;
          float s = 0.f;
#pragma unroll
          for (int tp = 0; tp < 8; ++tp)
            s = fdot2(wc[it][tp], qkvpk[gch * 8 + tp], s);
          acc[c] = s;
        }
#pragma unroll
        for (int pl = 0; pl < 4; ++pl)
          pre[pl * 630 + waddr[it]] = f2h2(acc[2 * pl], acc[2 * pl + 1]);
      }
    }
    __syncthreads();
#pragma unroll
    for (int pl = 0; pl < 4; ++pl) {
      int gpl = 16 + 4 * vc + pl;
      const unsigned int* wp = dwpk + gpl * 9;
      __half2 a0 = __floats2half2_rn(0.f, 0.f), a1 = a0;
      int base = pl * 630 + dwbase;
#pragma unroll
      for (int dy = 0; dy < 3; ++dy) {
        __half2 d0 = __builtin_bit_cast(__half2, pre[base + dy * 35 + 0]);
        __half2 d1 = __builtin_bit_cast(__half2, pre[base + dy * 35 + 1]);
        __half2 d2 = __builtin_bit_cast(__half2, pre[base + dy * 35 + 2]);
        __half2 d3 = __builtin_bit_cast(__half2, pre[base + dy * 35 + 3]);
        __half2 w0 = __builtin_bit_cast(__half2, wp[dy * 3 + 0]);
        __half2 w1 = __builtin_bit_cast(__half2, wp[dy * 3 + 1]);
        __half2 w2 = __builtin_bit_cast(__half2, wp[dy * 3 + 2]);
        a0 = __hfma2(w0, d0, a0); a0 = __hfma2(w1, d1, a0); a0 = __hfma2(w2, d2, a0);
        a1 = __hfma2(w0, d1, a1); a1 = __hfma2(w1, d2, a1); a1 = __hfma2(w2, d3, a1);
      }
      uint2 st2;
      st2.x = __builtin_bit_cast(unsigned int, a0);   // (chE,chO)@px0
      st2.y = __builtin_bit_cast(unsigned int, a1);   // @px1
      size_t idx = ((size_t)(bc * 8 + 4 * vc + pl) << 14) +
                   (size_t)((ty0 + iy) << 7) + tx0 + 2 * jx;
      *reinterpret_cast<uint2*>(vbuf + idx) = st2;
    }
    __syncthreads();   // pre reads done before next 1x1 writes
  }
}

// ---------------- K2: softmax -> packed fp16 attention rows ----------------
__global__ __launch_bounds__(256) void k_softmax(
    const float* __restrict__ Sacc, const float* __restrict__ Nacc,
    const float* __restrict__ temp, unsigned int* __restrict__ attnpk) {
  int idx = blockIdx.x * 256 + threadIdx.x;
  if (idx >= 512) return;
  int b = idx >> 2, hd = idx & 3;   // b = bt*64 + ci
  int bt = b >> 6, ci = b & 63;
  float tp = temp[hd];
  float iq[4], ik[4];
#pragma unroll
  for (int c = 0; c < 4; ++c) {
    iq[c] = 1.f / fmaxf(sqrtf(Nacc[(b << 5) + (hd << 2) + c]), 1e-12f);
    ik[c] = 1.f / fmaxf(sqrtf(Nacc[(b << 5) + 16 + (hd << 2) + c]), 1e-12f);
  }
  const float* Sp = Sacc + ((b << 2) + hd) * 16;
#pragma unroll
  for (int c = 0; c < 4; ++c) {
    float l[4];
#pragma unroll
    for (int d = 0; d < 4; ++d) l[d] = Sp[c * 4 + d] * iq[c] * ik[d] * tp;
    float m = fmaxf(fmaxf(l[0], l[1]), fmaxf(l[2], l[3]));
    float e0 = expf(l[0] - m), e1 = expf(l[1] - m);
    float e2 = expf(l[2] - m), e3 = expf(l[3] - m);
    float inv = 1.f / (e0 + e1 + e2 + e3);
    unsigned int* dst = attnpk + ((((bt * 4 + hd) * 4 + c) << 7) + ci * 2);
    dst[0] = f2h2(e0 * inv, e1 * inv);
    dst[1] = f2h2(e2 * inv, e3 * inv);
  }
}

// ---------------- K3: out = proj @ (attn . v) via packed dot2 ----------------
__global__ __launch_bounds__(256) void k_outproj(
    const unsigned int* __restrict__ vbuf, const unsigned int* __restrict__ attnpk,
    const unsigned int* __restrict__ projpk, float* __restrict__ out) {
  int comb = blockIdx.y;                 // bt*16 + hd*4 + c
  int bt = comb >> 4, hd = (comb >> 2) & 3, c = comb & 3;
  int px = (blockIdx.x << 8) + threadIdx.x;

  const unsigned int* apk = attnpk + (((bt * 4 + hd) * 4 + c) << 7);  // uniform
  float acc[64];
#pragma unroll
  for (int o = 0; o < 64; ++o) acc[o] = 0.f;

  size_t vbase = ((((size_t)bt * 512) + hd * 2) << 14) + px;
  for (int ci2 = 0; ci2 < 32; ++ci2) {
    size_t off0 = vbase + (((size_t)(2 * ci2) * 8) << 14);
    size_t off1 = off0 + ((size_t)8 << 14);
    unsigned int v0a = vbuf[off0];
    unsigned int v0b = vbuf[off0 + (1 << 14)];
    unsigned int v1a = vbuf[off1];
    unsigned int v1b = vbuf[off1 + (1 << 14)];
    float y0 = fdot2(v0a, apk[4 * ci2 + 0], fdot2(v0b, apk[4 * ci2 + 1], 0.f));
    float y1 = fdot2(v1a, apk[4 * ci2 + 2], fdot2(v1b, apk[4 * ci2 + 3], 0.f));
    unsigned int y2 = f2h2(y0, y1);
#pragma unroll
    for (int o = 0; o < 64; ++o)
      acc[o] = fdot2(y2, projpk[(o << 5) + ci2], acc[o]);   // SGPR-fed dot2
  }
  float* op = out + (((size_t)comb << 6) << 14) + px;
#pragma unroll
  for (int o = 0; o < 64; ++o) op[(size_t)o << 14] = acc[o];
}

extern "C" void kernel_launch(void* const* d_in, const int* in_sizes, int n_in,
                              void* d_out, int out_size, void* d_ws, size_t ws_size,
                              hipStream_t stream) {
  const float* x = (const float*)d_in[0];
  const float* lnw = (const float*)d_in[1];
  const float* lnb = (const float*)d_in[2];
  const float* qkvw = (const float*)d_in[3];
  const float* dww = (const float*)d_in[4];
  const float* projw = (const float*)d_in[5];
  const float* temp = (const float*)d_in[6];
  float* out = (float*)d_out;

  // workspace: vbuf 64 MiB | stats 4 MiB | Sacc 32K | Nacc 16K | attnpk 16K |
  //            projpk 8K | qkvpk 1.5K | dwpk 0.9K   (total ~68.1 MiB)
  unsigned int* vbuf = (unsigned int*)d_ws;
  char* tail = (char*)d_ws + 67108864ull;
  float4* stats4 = (float4*)tail;                         // 4 MiB
  float* Sacc = (float*)(tail + 4194304ull);              // 8192 f32
  float* Nacc = Sacc + 8192;                              // 4096 f32
  unsigned int* attnpk = (unsigned int*)(Nacc + 4096);    // 4096 u32
  unsigned int* projpk = attnpk + 4096;                   // 2048 u32
  unsigned int* qkvpk = projpk + 2048;                    // 384 u32
  unsigned int* dwpk = qkvpk + 384;                       // 216 u32

  hipMemsetAsync(Sacc, 0, (8192 + 4096) * sizeof(float), stream);
  k_stats<<<dim3(1024), dim3(256), 0, stream>>>((const float2*)x, stats4);
  k_wpack<<<dim3(11), dim3(256), 0, stream>>>(qkvw, dww, projw, qkvpk, dwpk, projpk);
  k_fused<<<dim3(32, 128), dim3(256), 0, stream>>>(
      x, (const float2*)stats4, lnw, lnb, qkvpk, dwpk, vbuf, Sacc, Nacc);
  k_softmax<<<dim3(2), dim3(256), 0, stream>>>(Sacc, Nacc, temp, attnpk);
  k_outproj<<<dim3(64, 32), dim3(256), 0, stream>>>(vbuf, attnpk, projpk, out);
}